// Round 3
// baseline (212.616 us; speedup 1.0000x reference)
//
#include <hip/hip_runtime.h>
#include <hip/hip_bf16.h>
#include <stdint.h>

// Problem constants (B, L, D, T) = (2, 2048, 1536, 2)
#define B_ 2
#define L_ 2048
#define D_ 1536

typedef __attribute__((ext_vector_type(4))) float  f32x4;
typedef __attribute__((ext_vector_type(8))) __bf16 bf16x8;

__device__ __forceinline__ unsigned short f2bf(float f) {
  unsigned int u = __float_as_uint(f);
  u += 0x7fffu + ((u >> 16) & 1u);   // RNE
  return (unsigned short)(u >> 16);
}

// Stage 1: hs(fp32) -> X(bf16), and P[t] = hs * Wp[t] (bf16), t in {0,1}
__global__ __launch_bounds__(256) void conv_kernel(
    const float* __restrict__ hs, const float* __restrict__ W,
    unsigned short* __restrict__ X, unsigned short* __restrict__ P) {
  const int idx  = blockIdx.x * 256 + threadIdx.x;
  const int base = idx * 4;                       // 4 consecutive d per thread
  const int d    = base % D_;                     // row-major (b,i,d); D_%4==0
  const float4 h  = *(const float4*)(hs + base);
  const float4 w0 = *(const float4*)(W + d);            // Wp[0, d..d+3]
  const float4 w1 = *(const float4*)(W + 2 * D_ + d);   // Wp[1, d..d+3]
  ushort4 x, p0, p1;
  x.x  = f2bf(h.x);        x.y  = f2bf(h.y);        x.z  = f2bf(h.z);        x.w  = f2bf(h.w);
  p0.x = f2bf(h.x * w0.x); p0.y = f2bf(h.y * w0.y); p0.z = f2bf(h.z * w0.z); p0.w = f2bf(h.w * w0.w);
  p1.x = f2bf(h.x * w1.x); p1.y = f2bf(h.y * w1.y); p1.z = f2bf(h.z * w1.z); p1.w = f2bf(h.w * w1.w);
  *(ushort4*)(X + base) = x;
  *(ushort4*)(P + base) = p0;
  *(ushort4*)(P + (size_t)B_ * L_ * D_ + base) = p1;
}

__device__ __forceinline__ void async16(const void* g, const void* l) {
  __builtin_amdgcn_global_load_lds(
      (const __attribute__((address_space(1))) void*)g,
      (__attribute__((address_space(3))) void*)l, 16, 0, 0);
}

// Stage 2: out[b,i,j,t] = P_t[b,i,:] . X[b,j,:] + bias[t], symmetric in (i,j).
// Only upper-triangle 128x128 tiles (ti<=tj) are computed: 136 tiles x 2t x 2b
// = 544 blocks. Off-diagonal tiles write both (i,j) and the (j,i) mirror; the
// mirror goes through an LDS transpose (4 panels of 32 cols, stride 129 pad)
// so global stores stay row-contiguous. Double-buffered K-loop, BK=32.
__global__ __launch_bounds__(256, 4) void gemm_kernel(
    const unsigned short* __restrict__ X, const unsigned short* __restrict__ P,
    const float* __restrict__ bias, float* __restrict__ out) {
  __shared__ __align__(16) unsigned char smem[32768];
  unsigned short* As = (unsigned short*)smem;             // 2 x 4096 shorts
  unsigned short* Bs = (unsigned short*)(smem + 16384);   // 2 x 4096 shorts
  float*          Tr = (float*)smem;                      // 32x129 fp32 panel

  const int tid = threadIdx.x;

  // ---- block-id decode: id = tri*4 + (bz*2 + t); tri -> (ti<=tj)
  const int id  = blockIdx.x;
  int rem = id >> 2;
  const int t   = id & 1;
  const int bz  = (id >> 1) & 1;
  int ti = 0;
  while (rem >= 16 - ti) { rem -= 16 - ti; ++ti; }
  const int tj = ti + rem;
  const int I0 = ti * 128;
  const int J0 = tj * 128;

  // ---- staging geometry: thread tid fills LDS slot (row=tid>>2, slot=tid&3),
  // 16B per load. XOR swizzle: slot cs holds global chunk gc = cs ^ ((row>>1)&3).
  const int srow = tid >> 2;
  const int cs   = tid & 3;
  const int gc   = cs ^ ((srow >> 1) & 3);
  const int scol = gc * 8;                       // element offset of d-chunk
  const int ldst = tid * 8;                      // LDS dest slot (elements)

  const unsigned short* pA =
      P + (size_t)t * B_ * L_ * D_ + ((size_t)(bz * L_ + I0 + srow)) * D_ + scol;
  const unsigned short* pB =
      X + ((size_t)(bz * L_ + J0 + srow)) * D_ + scol;

  // ---- compute geometry (2x2 waves of 64x64)
  const int lane = tid & 63;
  const int w    = tid >> 6;
  const int wi   = (w & 1) * 64;
  const int wj   = (w >> 1) * 64;
  const int lr   = lane & 15;
  const int q    = lane >> 4;
  const int ccol = (q ^ ((lr >> 1) & 3)) * 8;    // read-side swizzle

  int aoff[4], boff[4];
#pragma unroll
  for (int m = 0; m < 4; ++m) {
    aoff[m] = (wi + m * 16 + lr) * 32 + ccol;
    boff[m] = (wj + m * 16 + lr) * 32 + ccol;
  }

  f32x4 acc[4][4] = {};

#define STAGE(buf, koff)                                             \
  do {                                                               \
    async16(pA + (koff),           As + (buf) * 4096 + ldst);        \
    async16(pA + (koff) + 64 * D_, As + (buf) * 4096 + ldst + 2048); \
    async16(pB + (koff),           Bs + (buf) * 4096 + ldst);        \
    async16(pB + (koff) + 64 * D_, Bs + (buf) * 4096 + ldst + 2048); \
  } while (0)

  STAGE(0, 0);
  for (int k = 0; k < D_ / 32; ++k) {
    __syncthreads();                 // drains prefetch (vmcnt0) + prior reads
    if (k < D_ / 32 - 1) STAGE((k + 1) & 1, (k + 1) * 32);
    const unsigned short* Ab = As + (k & 1) * 4096;
    const unsigned short* Bb = Bs + (k & 1) * 4096;
    bf16x8 af[4], bf_[4];
#pragma unroll
    for (int m = 0; m < 4; ++m) af[m]  = *(const bf16x8*)(Ab + aoff[m]);
#pragma unroll
    for (int n = 0; n < 4; ++n) bf_[n] = *(const bf16x8*)(Bb + boff[n]);
#pragma unroll
    for (int m = 0; m < 4; ++m)
#pragma unroll
      for (int n = 0; n < 4; ++n)
        acc[m][n] = __builtin_amdgcn_mfma_f32_16x16x32_bf16(af[m], bf_[n], acc[m][n], 0, 0, 0);
  }
#undef STAGE

  // ---- epilogue 1: main tile. C/D layout col(j)=lane&15, row(i)=quad*4+reg
  const float bt = bias[t];
#pragma unroll
  for (int m = 0; m < 4; ++m) {
#pragma unroll
    for (int r = 0; r < 4; ++r) {
      const int i = I0 + wi + m * 16 + q * 4 + r;
      float* orow = out + (((size_t)(bz * L_ + i)) * L_ + (J0 + wj + lr)) * 2 + t;
#pragma unroll
      for (int n = 0; n < 4; ++n) orow[n * 32] = acc[m][n][r] + bt;
    }
  }

  // ---- epilogue 2: mirror tile (j,i) via LDS transpose, skip diagonal
  if (ti != tj) {
#pragma unroll
    for (int p = 0; p < 4; ++p) {               // panel = orig cols [32p, 32p+32)
      const int c0 = p * 32;
      __syncthreads();                           // Tr free (K-loop or prev panel done)
#pragma unroll
      for (int n = 0; n < 4; ++n) {
        // wave-uniform test: 16-aligned col range lies wholly in/out of panel
        if (((wj + n * 16) >> 5) == p) {
          const int col = wj + n * 16 + lr - c0;  // 0..31
#pragma unroll
          for (int m = 0; m < 4; ++m)
#pragma unroll
            for (int r = 0; r < 4; ++r)
              Tr[col * 129 + (wi + m * 16 + q * 4 + r)] = acc[m][n][r] + bt;
        }
      }
      __syncthreads();                           // panel fully written
      const int mr  = tid >> 3;                  // 0..31 mirror-row within panel
      const int seg = tid & 7;                   // 0..7 (16 cols each)
      const int jj  = J0 + c0 + mr;              // mirror i-index (orig col)
      float* obase = out + (((size_t)(bz * L_ + jj)) * L_ + I0 + seg * 16) * 2 + t;
#pragma unroll
      for (int e = 0; e < 16; ++e)
        obase[e * 2] = Tr[mr * 129 + seg * 16 + e];
    }
  }
}

extern "C" void kernel_launch(void* const* d_in, const int* in_sizes, int n_in,
                              void* d_out, int out_size, void* d_ws, size_t ws_size,
                              hipStream_t stream) {
  const float* hs   = (const float*)d_in[0];
  const float* W    = (const float*)d_in[1];
  const float* bias = (const float*)d_in[2];

  unsigned short* X = (unsigned short*)d_ws;                 // B*L*D bf16
  unsigned short* P = X + (size_t)B_ * L_ * D_;              // T*B*L*D bf16

  const int nconv = (B_ * L_ * D_ / 4) / 256;                // 6144 blocks
  conv_kernel<<<nconv, 256, 0, stream>>>(hs, W, X, P);

  gemm_kernel<<<544, 256, 0, stream>>>(X, P, bias, (float*)d_out);
}

// Round 4
// 197.537 us; speedup vs baseline: 1.0763x; 1.0763x over previous
//
#include <hip/hip_runtime.h>
#include <hip/hip_bf16.h>
#include <stdint.h>

// Problem constants (B, L, D, T) = (2, 2048, 1536, 2)
#define B_ 2
#define L_ 2048
#define D_ 1536

typedef __attribute__((ext_vector_type(4))) float  f32x4;
typedef __attribute__((ext_vector_type(8))) __bf16 bf16x8;

__device__ __forceinline__ unsigned short f2bf(float f) {
  unsigned int u = __float_as_uint(f);
  u += 0x7fffu + ((u >> 16) & 1u);   // RNE
  return (unsigned short)(u >> 16);
}

// Stage 1: hs(fp32) -> X(bf16), and P[t] = hs * Wp[t] (bf16), t in {0,1}
__global__ __launch_bounds__(256) void conv_kernel(
    const float* __restrict__ hs, const float* __restrict__ W,
    unsigned short* __restrict__ X, unsigned short* __restrict__ P) {
  const int idx  = blockIdx.x * 256 + threadIdx.x;
  const int base = idx * 4;                       // 4 consecutive d per thread
  const int d    = base % D_;                     // row-major (b,i,d); D_%4==0
  const float4 h  = *(const float4*)(hs + base);
  const float4 w0 = *(const float4*)(W + d);            // Wp[0, d..d+3]
  const float4 w1 = *(const float4*)(W + 2 * D_ + d);   // Wp[1, d..d+3]
  ushort4 x, p0, p1;
  x.x  = f2bf(h.x);        x.y  = f2bf(h.y);        x.z  = f2bf(h.z);        x.w  = f2bf(h.w);
  p0.x = f2bf(h.x * w0.x); p0.y = f2bf(h.y * w0.y); p0.z = f2bf(h.z * w0.z); p0.w = f2bf(h.w * w0.w);
  p1.x = f2bf(h.x * w1.x); p1.y = f2bf(h.y * w1.y); p1.z = f2bf(h.z * w1.z); p1.w = f2bf(h.w * w1.w);
  *(ushort4*)(X + base) = x;
  *(ushort4*)(P + base) = p0;
  *(ushort4*)(P + (size_t)B_ * L_ * D_ + base) = p1;
}

__device__ __forceinline__ void async16(const void* g, const void* l) {
  __builtin_amdgcn_global_load_lds(
      (const __attribute__((address_space(1))) void*)g,
      (__attribute__((address_space(3))) void*)l, 16, 0, 0);
}

// Stage 2 (de-fused t): out[b,i,j,t] = P_t[b,i,:] . X[b,j,:] + bias[t]
// Grid 1024, 256 threads, 128x128 tile, BK=32. B-tile staged through
// double-buffered LDS (16 KB); A-fragments read DIRECTLY from global —
// each lane's frag is a contiguous 16B load, wave-twin shares the rows
// (L1 hit), A-tile reused across 16 j-tiles (L2 hit). This halves LDS
// traffic (the R2 bottleneck pipe) and shrinks the barrier drain queue.
__global__ __launch_bounds__(256, 4) void gemm_kernel(
    const unsigned short* __restrict__ X, const unsigned short* __restrict__ P,
    const float* __restrict__ bias, float* __restrict__ out) {
  __shared__ unsigned short Bs[2 * 128 * 32];   // 16 KB double-buffered B

  const int tid = threadIdx.x;

  // ---- block-id decode: id = xcd + 8*(t + 2*(within + 16*pp))
  // t-pairs of one (b,i,j) tile are 8 ids apart (same XCD) -> stores merge.
  const int id     = blockIdx.x;
  const int xcd    = id & 7;
  const int u      = id >> 3;
  const int t      = u & 1;
  const int v      = u >> 1;          // 0..63
  const int within = v & 15;          // position in 4x4 tile patch
  const int pp     = v >> 4;          // 0..3
  const int Pp     = pp * 8 + xcd;    // patch 0..31 (16 per b)
  const int bz     = Pp >> 4;
  const int pr     = Pp & 15;
  const int I0     = ((pr >> 2) * 4 + (within >> 2)) * 128;
  const int J0     = ((pr & 3)  * 4 + (within & 3))  * 128;

  // ---- B staging geometry: thread tid fills slot (row=tid>>2, slot=tid&3),
  // 16B per load. XOR swizzle: slot cs holds global chunk gc = cs ^ ((row>>1)&3).
  const int srow = tid >> 2;
  const int cs   = tid & 3;
  const int gc   = cs ^ ((srow >> 1) & 3);
  const int scol = gc * 8;
  const int ldst = tid * 8;

  const unsigned short* pB = X + ((size_t)(bz * L_ + J0 + srow)) * D_ + scol;

  // ---- compute geometry (2x2 waves of 64x64)
  const int lane = tid & 63;
  const int w    = tid >> 6;
  const int wi   = (w & 1) * 64;
  const int wj   = (w >> 1) * 64;
  const int lr   = lane & 15;
  const int q    = lane >> 4;
  const int ccol = (q ^ ((lr >> 1) & 3)) * 8;    // read-side swizzle (B)

  int boff[4];
#pragma unroll
  for (int n = 0; n < 4; ++n) boff[n] = (wj + n * 16 + lr) * 32 + ccol;

  // A direct-global: frag m at pA + m*16*D_ + k*32 (16B contiguous per lane)
  const unsigned short* pA = P + (size_t)t * B_ * L_ * D_ +
      ((size_t)(bz * L_ + I0 + wi + lr)) * D_ + q * 8;

  f32x4 acc[4][4] = {};

#define STAGE(buf, koff)                                             \
  do {                                                               \
    async16(pB + (koff),           Bs + (buf) * 4096 + ldst);        \
    async16(pB + (koff) + 64 * D_, Bs + (buf) * 4096 + ldst + 2048); \
  } while (0)

  STAGE(0, 0);
  for (int k = 0; k < D_ / 32; ++k) {
    __syncthreads();                 // B(k) staged; prior buf reads done
    if (k < D_ / 32 - 1) STAGE((k + 1) & 1, (k + 1) * 32);
    bf16x8 af[4], bf_[4];
#pragma unroll
    for (int m = 0; m < 4; ++m)
      af[m] = *(const bf16x8*)(pA + m * 16 * D_ + k * 32);
    const unsigned short* Bb = Bs + (k & 1) * 4096;
#pragma unroll
    for (int n = 0; n < 4; ++n) bf_[n] = *(const bf16x8*)(Bb + boff[n]);
#pragma unroll
    for (int m = 0; m < 4; ++m)
#pragma unroll
      for (int n = 0; n < 4; ++n)
        acc[m][n] = __builtin_amdgcn_mfma_f32_16x16x32_bf16(af[m], bf_[n], acc[m][n], 0, 0, 0);
  }
#undef STAGE

  // ---- epilogue: C/D layout col(j)=lane&15, row(i)=quad*4+reg  (R2, proven)
  const float bt = bias[t];
#pragma unroll
  for (int m = 0; m < 4; ++m) {
#pragma unroll
    for (int r = 0; r < 4; ++r) {
      const int i = I0 + wi + m * 16 + q * 4 + r;
      float* orow = out + (((size_t)(bz * L_ + i)) * L_ + (J0 + wj + lr)) * 2 + t;
#pragma unroll
      for (int n = 0; n < 4; ++n) orow[n * 32] = acc[m][n][r] + bt;
    }
  }
}

extern "C" void kernel_launch(void* const* d_in, const int* in_sizes, int n_in,
                              void* d_out, int out_size, void* d_ws, size_t ws_size,
                              hipStream_t stream) {
  const float* hs   = (const float*)d_in[0];
  const float* W    = (const float*)d_in[1];
  const float* bias = (const float*)d_in[2];

  unsigned short* X = (unsigned short*)d_ws;                 // B*L*D bf16
  unsigned short* P = X + (size_t)B_ * L_ * D_;              // T*B*L*D bf16

  const int nconv = (B_ * L_ * D_ / 4) / 256;                // 6144 blocks
  conv_kernel<<<nconv, 256, 0, stream>>>(hs, W, X, P);

  gemm_kernel<<<1024, 256, 0, stream>>>(X, P, bias, (float*)d_out);
}

// Round 5
// 150.881 us; speedup vs baseline: 1.4092x; 1.3092x over previous
//
#include <hip/hip_runtime.h>
#include <hip/hip_bf16.h>
#include <stdint.h>

// Problem constants (B, L, D, T) = (2, 2048, 1536, 2)
#define B_ 2
#define L_ 2048
#define D_ 1536

typedef __attribute__((ext_vector_type(4))) float  f32x4;
typedef __attribute__((ext_vector_type(8))) __bf16 bf16x8;

__device__ __forceinline__ unsigned short f2bf(float f) {
  unsigned int u = __float_as_uint(f);
  u += 0x7fffu + ((u >> 16) & 1u);   // RNE
  return (unsigned short)(u >> 16);
}

// Stage 1: hs(fp32) -> X(bf16), and P[t] = hs * Wp[t] (bf16), t in {0,1}
__global__ __launch_bounds__(256) void conv_kernel(
    const float* __restrict__ hs, const float* __restrict__ W,
    unsigned short* __restrict__ X, unsigned short* __restrict__ P) {
  const int idx  = blockIdx.x * 256 + threadIdx.x;
  const int base = idx * 4;                       // 4 consecutive d per thread
  const int d    = base % D_;                     // row-major (b,i,d); D_%4==0
  const float4 h  = *(const float4*)(hs + base);
  const float4 w0 = *(const float4*)(W + d);            // Wp[0, d..d+3]
  const float4 w1 = *(const float4*)(W + 2 * D_ + d);   // Wp[1, d..d+3]
  ushort4 x, p0, p1;
  x.x  = f2bf(h.x);        x.y  = f2bf(h.y);        x.z  = f2bf(h.z);        x.w  = f2bf(h.w);
  p0.x = f2bf(h.x * w0.x); p0.y = f2bf(h.y * w0.y); p0.z = f2bf(h.z * w0.z); p0.w = f2bf(h.w * w0.w);
  p1.x = f2bf(h.x * w1.x); p1.y = f2bf(h.y * w1.y); p1.z = f2bf(h.z * w1.z); p1.w = f2bf(h.w * w1.w);
  *(ushort4*)(X + base) = x;
  *(ushort4*)(P + base) = p0;
  *(ushort4*)(P + (size_t)B_ * L_ * D_ + base) = p1;
}

__device__ __forceinline__ void async16(const void* g, const void* l) {
  __builtin_amdgcn_global_load_lds(
      (const __attribute__((address_space(1))) void*)g,
      (__attribute__((address_space(3))) void*)l, 16, 0, 0);
}

// Stage 2 (fused t, dbuf): out[b,i,j,(t0,t1)] = P_t[b,i,:].X[b,j,:] + bias[t]
// Grid 512, 256 threads, 128x128 tile x both t, BK=32, double-buffered LDS
// (A0/A1/B = 48 KB), ONE barrier per K-iter. Per wave per iter: 32 MFMA on
// 12 ds_read_b128 (vs R2's 16 on 8) -> fewer barriers & LDS reads per MFMA,
// 2x longer compute phase so the 6-deep async16 queue drains free.
// Stores are dense float2 (R1 measured WRITE = 64 MB exact).
__global__ __launch_bounds__(256, 2) void gemm_kernel(
    const unsigned short* __restrict__ X, const unsigned short* __restrict__ P,
    const float* __restrict__ bias, float2* __restrict__ out) {
  __shared__ unsigned short As0[2 * 128 * 32];
  __shared__ unsigned short As1[2 * 128 * 32];
  __shared__ unsigned short Bs [2 * 128 * 32];

  const int tid = threadIdx.x;

  // ---- block-id decode: id = xcd + 8*(within + 16*pp); XCD-aware patches
  const int id     = blockIdx.x;
  const int xcd    = id & 7;
  const int u      = id >> 3;
  const int within = u & 15;          // position in 4x4 tile patch
  const int pp     = u >> 4;          // 0..3
  const int Pp     = pp * 8 + xcd;    // patch 0..31 (16 per b)
  const int bz     = Pp >> 4;
  const int pr     = Pp & 15;
  const int I0     = ((pr >> 2) * 4 + (within >> 2)) * 128;
  const int J0     = ((pr & 3)  * 4 + (within & 3))  * 128;

  // ---- staging geometry: thread tid fills slot (row=tid>>2, slot=tid&3),
  // 16B per load. XOR swizzle: slot cs holds global chunk gc = cs ^ ((row>>1)&3).
  const int srow = tid >> 2;
  const int cs   = tid & 3;
  const int gc   = cs ^ ((srow >> 1) & 3);
  const int scol = gc * 8;
  const int ldst = tid * 8;

  const size_t planeB = (size_t)B_ * L_ * D_;
  const unsigned short* pA0 = P + ((size_t)(bz * L_ + I0 + srow)) * D_ + scol;
  const unsigned short* pA1 = pA0 + planeB;
  const unsigned short* pB  = X + ((size_t)(bz * L_ + J0 + srow)) * D_ + scol;

  // ---- compute geometry (2x2 waves of 64x64)
  const int lane = tid & 63;
  const int w    = tid >> 6;
  const int wi   = (w & 1) * 64;
  const int wj   = (w >> 1) * 64;
  const int lr   = lane & 15;
  const int q    = lane >> 4;
  const int ccol = (q ^ ((lr >> 1) & 3)) * 8;    // read-side swizzle

  int aoff[4], boff[4];
#pragma unroll
  for (int m = 0; m < 4; ++m) {
    aoff[m] = (wi + m * 16 + lr) * 32 + ccol;
    boff[m] = (wj + m * 16 + lr) * 32 + ccol;
  }

  f32x4 acc0[4][4] = {};
  f32x4 acc1[4][4] = {};

#define STAGE(buf, koff)                                              \
  do {                                                                \
    async16(pA0 + (koff),           As0 + (buf) * 4096 + ldst);       \
    async16(pA0 + (koff) + 64 * D_, As0 + (buf) * 4096 + ldst + 2048);\
    async16(pA1 + (koff),           As1 + (buf) * 4096 + ldst);       \
    async16(pA1 + (koff) + 64 * D_, As1 + (buf) * 4096 + ldst + 2048);\
    async16(pB  + (koff),           Bs  + (buf) * 4096 + ldst);       \
    async16(pB  + (koff) + 64 * D_, Bs  + (buf) * 4096 + ldst + 2048);\
  } while (0)

  STAGE(0, 0);
  for (int k = 0; k < D_ / 32; ++k) {
    __syncthreads();                 // stage k done; prior buf reads done
    if (k < D_ / 32 - 1) STAGE((k + 1) & 1, (k + 1) * 32);
    const unsigned short* A0b = As0 + (k & 1) * 4096;
    const unsigned short* A1b = As1 + (k & 1) * 4096;
    const unsigned short* Bb  = Bs  + (k & 1) * 4096;
    bf16x8 a0f[4], a1f[4], bf_[4];
#pragma unroll
    for (int m = 0; m < 4; ++m) {
      a0f[m] = *(const bf16x8*)(A0b + aoff[m]);
      a1f[m] = *(const bf16x8*)(A1b + aoff[m]);
    }
#pragma unroll
    for (int n = 0; n < 4; ++n) bf_[n] = *(const bf16x8*)(Bb + boff[n]);
#pragma unroll
    for (int m = 0; m < 4; ++m)
#pragma unroll
      for (int n = 0; n < 4; ++n) {
        acc0[m][n] = __builtin_amdgcn_mfma_f32_16x16x32_bf16(a0f[m], bf_[n], acc0[m][n], 0, 0, 0);
        acc1[m][n] = __builtin_amdgcn_mfma_f32_16x16x32_bf16(a1f[m], bf_[n], acc1[m][n], 0, 0, 0);
      }
  }
#undef STAGE

  // ---- epilogue: C/D layout col(j)=lane&15, row(i)=quad*4+reg; dense float2
  const float bias0 = bias[0], bias1 = bias[1];
#pragma unroll
  for (int m = 0; m < 4; ++m) {
#pragma unroll
    for (int r = 0; r < 4; ++r) {
      const int i = I0 + wi + m * 16 + q * 4 + r;
      float2* orow = out + (size_t)(bz * L_ + i) * L_ + (J0 + wj + lr);
#pragma unroll
      for (int n = 0; n < 4; ++n) {
        float2 v;
        v.x = acc0[m][n][r] + bias0;
        v.y = acc1[m][n][r] + bias1;
        orow[n * 16] = v;
      }
    }
  }
}

extern "C" void kernel_launch(void* const* d_in, const int* in_sizes, int n_in,
                              void* d_out, int out_size, void* d_ws, size_t ws_size,
                              hipStream_t stream) {
  const float* hs   = (const float*)d_in[0];
  const float* W    = (const float*)d_in[1];
  const float* bias = (const float*)d_in[2];

  unsigned short* X = (unsigned short*)d_ws;                 // B*L*D bf16
  unsigned short* P = X + (size_t)B_ * L_ * D_;              // T*B*L*D bf16

  const int nconv = (B_ * L_ * D_ / 4) / 256;                // 6144 blocks
  conv_kernel<<<nconv, 256, 0, stream>>>(hs, W, X, P);

  gemm_kernel<<<512, 256, 0, stream>>>(X, P, bias, (float2*)d_out);
}

// Round 6
// 141.667 us; speedup vs baseline: 1.5008x; 1.0650x over previous
//
#include <hip/hip_runtime.h>
#include <hip/hip_bf16.h>
#include <stdint.h>

// Problem constants (B, L, D, T) = (2, 2048, 1536, 2)
#define B_ 2
#define L_ 2048
#define D_ 1536

typedef __attribute__((ext_vector_type(4))) float  f32x4;
typedef __attribute__((ext_vector_type(8))) __bf16 bf16x8;

__device__ __forceinline__ unsigned short f2bf(float f) {
  unsigned int u = __float_as_uint(f);
  u += 0x7fffu + ((u >> 16) & 1u);   // RNE
  return (unsigned short)(u >> 16);
}

// Stage 1: hs(fp32) -> X(bf16), and P[t] = hs * Wp[t] (bf16), t in {0,1}
__global__ __launch_bounds__(256) void conv_kernel(
    const float* __restrict__ hs, const float* __restrict__ W,
    unsigned short* __restrict__ X, unsigned short* __restrict__ P) {
  const int idx  = blockIdx.x * 256 + threadIdx.x;
  const int base = idx * 4;                       // 4 consecutive d per thread
  const int d    = base % D_;                     // row-major (b,i,d); D_%4==0
  const float4 h  = *(const float4*)(hs + base);
  const float4 w0 = *(const float4*)(W + d);            // Wp[0, d..d+3]
  const float4 w1 = *(const float4*)(W + 2 * D_ + d);   // Wp[1, d..d+3]
  ushort4 x, p0, p1;
  x.x  = f2bf(h.x);        x.y  = f2bf(h.y);        x.z  = f2bf(h.z);        x.w  = f2bf(h.w);
  p0.x = f2bf(h.x * w0.x); p0.y = f2bf(h.y * w0.y); p0.z = f2bf(h.z * w0.z); p0.w = f2bf(h.w * w0.w);
  p1.x = f2bf(h.x * w1.x); p1.y = f2bf(h.y * w1.y); p1.z = f2bf(h.z * w1.z); p1.w = f2bf(h.w * w1.w);
  *(ushort4*)(X + base) = x;
  *(ushort4*)(P + base) = p0;
  *(ushort4*)(P + (size_t)B_ * L_ * D_ + base) = p1;
}

// Stage 2 (fused t, reg-staged pipeline):
// out[b,i,j,(t0,t1)] = P_t[b,i,:].X[b,j,:] + bias[t]
// Grid 512, 256 threads, 128x128 x both t, BK=32, double-buffered LDS.
// Staging is global_load_dwordx4 -> VGPR -> ds_write_b128 with prefetch
// distance = 1 full K-iter, so __syncthreads only waits lgkm (LDS writes),
// NOT vmcnt(0) -- the barrier no longer drains the HBM/L2 queue (the
// structural ~20% stall of the global_load_lds version).
__global__ __launch_bounds__(256, 2) void gemm_kernel(
    const unsigned short* __restrict__ X, const unsigned short* __restrict__ P,
    const float* __restrict__ bias, float2* __restrict__ out) {
  __shared__ unsigned short As0[2 * 128 * 32];
  __shared__ unsigned short As1[2 * 128 * 32];
  __shared__ unsigned short Bs [2 * 128 * 32];

  const int tid = threadIdx.x;

  // ---- block-id decode: id = xcd + 8*(within + 16*pp); XCD-aware patches
  const int id     = blockIdx.x;
  const int xcd    = id & 7;
  const int u      = id >> 3;
  const int within = u & 15;
  const int pp     = u >> 4;
  const int Pp     = pp * 8 + xcd;
  const int bz     = Pp >> 4;
  const int pr     = Pp & 15;
  const int I0     = ((pr >> 2) * 4 + (within >> 2)) * 128;
  const int J0     = ((pr & 3)  * 4 + (within & 3))  * 128;

  // ---- staging geometry: thread tid fills slot (row=tid>>2, slot=tid&3),
  // 16B per thread. XOR swizzle lives in the GLOBAL address: slot cs holds
  // global chunk gc = cs ^ ((row>>1)&3); LDS side stays linear (ldst=tid*8).
  const int srow = tid >> 2;
  const int cs   = tid & 3;
  const int gc   = cs ^ ((srow >> 1) & 3);
  const int scol = gc * 8;
  const int ldst = tid * 8;

  const size_t planeB = (size_t)B_ * L_ * D_;
  const unsigned short* pA0 = P + ((size_t)(bz * L_ + I0 + srow)) * D_ + scol;
  const unsigned short* pA1 = pA0 + planeB;
  const unsigned short* pB  = X + ((size_t)(bz * L_ + J0 + srow)) * D_ + scol;

  // ---- compute geometry (2x2 waves of 64x64, both t-planes per wave)
  const int lane = tid & 63;
  const int w    = tid >> 6;
  const int wi   = (w & 1) * 64;
  const int wj   = (w >> 1) * 64;
  const int lr   = lane & 15;
  const int q    = lane >> 4;
  const int ccol = (q ^ ((lr >> 1) & 3)) * 8;    // read-side swizzle

  int aoff[4], boff[4];
#pragma unroll
  for (int m = 0; m < 4; ++m) {
    aoff[m] = (wi + m * 16 + lr) * 32 + ccol;
    boff[m] = (wj + m * 16 + lr) * 32 + ccol;
  }

  f32x4 acc0[4][4] = {};
  f32x4 acc1[4][4] = {};

  uint4 ra0l, ra0h, ra1l, ra1h, rbl, rbh;   // reg set 0
  uint4 sa0l, sa0h, sa1l, sa1h, sbl, sbh;   // reg set 1

#define GLOAD0(koff)                                      \
  do {                                                    \
    ra0l = *(const uint4*)(pA0 + (koff));                 \
    ra0h = *(const uint4*)(pA0 + (koff) + 64 * D_);       \
    ra1l = *(const uint4*)(pA1 + (koff));                 \
    ra1h = *(const uint4*)(pA1 + (koff) + 64 * D_);       \
    rbl  = *(const uint4*)(pB  + (koff));                 \
    rbh  = *(const uint4*)(pB  + (koff) + 64 * D_);       \
  } while (0)
#define GLOAD1(koff)                                      \
  do {                                                    \
    sa0l = *(const uint4*)(pA0 + (koff));                 \
    sa0h = *(const uint4*)(pA0 + (koff) + 64 * D_);       \
    sa1l = *(const uint4*)(pA1 + (koff));                 \
    sa1h = *(const uint4*)(pA1 + (koff) + 64 * D_);       \
    sbl  = *(const uint4*)(pB  + (koff));                 \
    sbh  = *(const uint4*)(pB  + (koff) + 64 * D_);       \
  } while (0)
#define DSW(buf, A0L, A0H, A1L, A1H, BL, BH)              \
  do {                                                    \
    *(uint4*)(As0 + (buf) * 4096 + ldst)        = A0L;    \
    *(uint4*)(As0 + (buf) * 4096 + ldst + 2048) = A0H;    \
    *(uint4*)(As1 + (buf) * 4096 + ldst)        = A1L;    \
    *(uint4*)(As1 + (buf) * 4096 + ldst + 2048) = A1H;    \
    *(uint4*)(Bs  + (buf) * 4096 + ldst)        = BL;     \
    *(uint4*)(Bs  + (buf) * 4096 + ldst + 2048) = BH;     \
  } while (0)
#define COMPUTE(buf)                                                           \
  do {                                                                         \
    const unsigned short* A0b = As0 + (buf) * 4096;                            \
    const unsigned short* A1b = As1 + (buf) * 4096;                            \
    const unsigned short* Bb  = Bs  + (buf) * 4096;                            \
    bf16x8 a0f[4], a1f[4], bf_[4];                                             \
    _Pragma("unroll") for (int m = 0; m < 4; ++m) {                            \
      a0f[m] = *(const bf16x8*)(A0b + aoff[m]);                                \
      a1f[m] = *(const bf16x8*)(A1b + aoff[m]);                                \
    }                                                                          \
    _Pragma("unroll") for (int n = 0; n < 4; ++n)                              \
      bf_[n] = *(const bf16x8*)(Bb + boff[n]);                                 \
    _Pragma("unroll") for (int m = 0; m < 4; ++m)                              \
      _Pragma("unroll") for (int n = 0; n < 4; ++n) {                          \
        acc0[m][n] = __builtin_amdgcn_mfma_f32_16x16x32_bf16(a0f[m], bf_[n],   \
                                                             acc0[m][n], 0, 0, 0); \
        acc1[m][n] = __builtin_amdgcn_mfma_f32_16x16x32_bf16(a1f[m], bf_[n],   \
                                                             acc1[m][n], 0, 0, 0); \
      }                                                                        \
  } while (0)

  GLOAD0(0);
  for (int k = 0; k < D_ / 32; k += 2) {
    // iter k: publish r-set to buf0, prefetch k+1 into s-set
    DSW(0, ra0l, ra0h, ra1l, ra1h, rbl, rbh);
    GLOAD1((k + 1) * 32);                     // k+1 <= 47 always
    __syncthreads();                          // lgkm drain only (no vmcnt)
    COMPUTE(0);
    // iter k+1: publish s-set to buf1, prefetch k+2 into r-set
    DSW(1, sa0l, sa0h, sa1l, sa1h, sbl, sbh);
    if (k + 2 < D_ / 32) GLOAD0((k + 2) * 32);
    __syncthreads();
    COMPUTE(1);
  }
#undef GLOAD0
#undef GLOAD1
#undef DSW
#undef COMPUTE

  // ---- epilogue: C/D layout col(j)=lane&15, row(i)=quad*4+reg; dense float2
  const float bias0 = bias[0], bias1 = bias[1];
#pragma unroll
  for (int m = 0; m < 4; ++m) {
#pragma unroll
    for (int r = 0; r < 4; ++r) {
      const int i = I0 + wi + m * 16 + q * 4 + r;
      float2* orow = out + (size_t)(bz * L_ + i) * L_ + (J0 + wj + lr);
#pragma unroll
      for (int n = 0; n < 4; ++n) {
        float2 v;
        v.x = acc0[m][n][r] + bias0;
        v.y = acc1[m][n][r] + bias1;
        orow[n * 16] = v;
      }
    }
  }
}

extern "C" void kernel_launch(void* const* d_in, const int* in_sizes, int n_in,
                              void* d_out, int out_size, void* d_ws, size_t ws_size,
                              hipStream_t stream) {
  const float* hs   = (const float*)d_in[0];
  const float* W    = (const float*)d_in[1];
  const float* bias = (const float*)d_in[2];

  unsigned short* X = (unsigned short*)d_ws;                 // B*L*D bf16
  unsigned short* P = X + (size_t)B_ * L_ * D_;              // T*B*L*D bf16

  const int nconv = (B_ * L_ * D_ / 4) / 256;                // 6144 blocks
  conv_kernel<<<nconv, 256, 0, stream>>>(hs, W, X, P);

  gemm_kernel<<<512, 256, 0, stream>>>(X, P, bias, (float2*)d_out);
}